// Round 1
// baseline (261.974 us; speedup 1.0000x reference)
//
#include <hip/hip_runtime.h>

typedef __attribute__((ext_vector_type(8))) short short8;
typedef __attribute__((ext_vector_type(4))) float floatx4;

#define D_NODE 64
#define D_OUT  64
// K segments: [0,64)=edges, [64,128)=recv, [128,192)=send, [192,224)=globals (folded into init)
#define NKSTEP 6            // 6 K-steps of 32 over the first 192 features
#define NFRAG  (NKSTEP * 4) // 24 B fragments (4 col-tiles of 16)
#define WP_BYTES (NFRAG * 64 * 8 * 2)  // 24576
#define ITERS 4             // 64-edge tiles per block iteration count

static __device__ __forceinline__ unsigned short f2bf(float x) {
    unsigned int u = __float_as_uint(x);
    unsigned int r = u + 0x7FFFu + ((u >> 16) & 1u);
    return (unsigned short)(r >> 16);
}

static __device__ __forceinline__ short8 load_cvt(const float* __restrict__ p) {
    float4 x = *(const float4*)p;
    float4 y = *(const float4*)(p + 4);
    short8 a;
    a[0] = (short)f2bf(x.x); a[1] = (short)f2bf(x.y);
    a[2] = (short)f2bf(x.z); a[3] = (short)f2bf(x.w);
    a[4] = (short)f2bf(y.x); a[5] = (short)f2bf(y.y);
    a[6] = (short)f2bf(y.z); a[7] = (short)f2bf(y.w);
    return a;
}

// Pack W[0:192,:] into bf16 MFMA B-fragment order:
//   frag fi = kstep*4 + ct; element (lane, j) = W[kstep*32 + (lane>>4)*8 + j][ct*16 + (lane&15)]
// Also compute glob_contrib[col] = sum_k globals[k]*W[192+k][col] + b[col].
__global__ void pack_kernel(const float* __restrict__ W, const float* __restrict__ b,
                            const float* __restrict__ g,
                            unsigned short* __restrict__ wp, float* __restrict__ gc) {
    int tid = blockIdx.x * 256 + threadIdx.x;
    if (tid < NFRAG * 64) {
        int lane  = tid & 63;
        int ct    = (tid >> 6) & 3;
        int kstep = tid >> 8;
        int kbase = kstep * 32 + (lane >> 4) * 8;
        int col   = ct * 16 + (lane & 15);
        short8 sv;
#pragma unroll
        for (int j = 0; j < 8; ++j)
            sv[j] = (short)f2bf(W[(size_t)(kbase + j) * D_OUT + col]);
        *(short8*)(wp + (size_t)tid * 8) = sv;
    } else if (tid < NFRAG * 64 + 64) {
        int col = tid - NFRAG * 64;
        float acc = b[col];
#pragma unroll
        for (int k = 0; k < 32; ++k)
            acc += g[k] * W[(size_t)(192 + k) * D_OUT + col];
        gc[col] = acc;
    }
}

__global__ __launch_bounds__(256) void edge_kernel(
    const float* __restrict__ edges, const float* __restrict__ nodes,
    const int* __restrict__ recv, const int* __restrict__ send,
    const unsigned short* __restrict__ wp, const float* __restrict__ gc,
    float* __restrict__ out, int E) {

    const int lane = threadIdx.x & 63;
    const int wave = threadIdx.x >> 6;

    // Hoist all 24 B-fragments into registers (L2-resident source, once per wave).
    short8 Bf[NFRAG];
#pragma unroll
    for (int fi = 0; fi < NFRAG; ++fi)
        Bf[fi] = *(const short8*)(wp + ((size_t)fi * 64 + lane) * 8);

    const int colbase = lane & 15;
    float gv[4];
#pragma unroll
    for (int ct = 0; ct < 4; ++ct) gv[ct] = gc[ct * 16 + colbase];

    const int koff = (lane >> 4) * 8;

    for (int it = 0; it < ITERS; ++it) {
        int ebase = (blockIdx.x * ITERS + it) * 64 + wave * 16;
        if (ebase >= E) break;

        int ea = ebase + (lane & 15);
        if (ea >= E) ea = E - 1;                 // clamp loads; stores guarded below
        int ri = recv[ea];
        int si = send[ea];

        const float* pe = edges + (size_t)ea * D_NODE + koff;
        const float* pr = nodes + (size_t)ri * D_NODE + koff;
        const float* ps = nodes + (size_t)si * D_NODE + koff;

        short8 A[NKSTEP];
        A[0] = load_cvt(pe);
        A[1] = load_cvt(pe + 32);
        A[2] = load_cvt(pr);
        A[3] = load_cvt(pr + 32);
        A[4] = load_cvt(ps);
        A[5] = load_cvt(ps + 32);

        floatx4 acc[4];
#pragma unroll
        for (int ct = 0; ct < 4; ++ct)
            acc[ct] = (floatx4){gv[ct], gv[ct], gv[ct], gv[ct]};

#pragma unroll
        for (int ks = 0; ks < NKSTEP; ++ks) {
#pragma unroll
            for (int ct = 0; ct < 4; ++ct)
                acc[ct] = __builtin_amdgcn_mfma_f32_16x16x32_bf16(
                    A[ks], Bf[ks * 4 + ct], acc[ct], 0, 0, 0);
        }

        int crow = ebase + (lane >> 4) * 4;
#pragma unroll
        for (int ct = 0; ct < 4; ++ct) {
#pragma unroll
            for (int r4 = 0; r4 < 4; ++r4) {
                int row = crow + r4;
                if (row < E)
                    out[(size_t)row * D_OUT + ct * 16 + colbase] = acc[ct][r4];
            }
        }
    }
}

extern "C" void kernel_launch(void* const* d_in, const int* in_sizes, int n_in,
                              void* d_out, int out_size, void* d_ws, size_t ws_size,
                              hipStream_t stream) {
    const float* edges = (const float*)d_in[0];
    const float* nodes = (const float*)d_in[1];
    const float* glob  = (const float*)d_in[2];
    const int*   recv  = (const int*)d_in[3];
    const int*   send  = (const int*)d_in[4];
    const float* W     = (const float*)d_in[5];
    const float* b     = (const float*)d_in[6];
    float* out = (float*)d_out;

    int E = in_sizes[0] / D_NODE;

    unsigned short* wp = (unsigned short*)d_ws;
    float* gc = (float*)((char*)d_ws + WP_BYTES);

    pack_kernel<<<7, 256, 0, stream>>>(W, b, glob, wp, gc);

    int nblk = (E + ITERS * 64 - 1) / (ITERS * 64);
    edge_kernel<<<nblk, 256, 0, stream>>>(edges, nodes, recv, send, wp, gc, out, E);
}

// Round 2
// 253.825 us; speedup vs baseline: 1.0321x; 1.0321x over previous
//
#include <hip/hip_runtime.h>

typedef __attribute__((ext_vector_type(8))) short short8;
typedef __attribute__((ext_vector_type(4))) float floatx4;

#define D_NODE 64
#define D_OUT  64
#define ITERS 4

static __device__ __forceinline__ unsigned short f2bf(float x) {
    unsigned int u = __float_as_uint(x);
    unsigned int r = u + 0x7FFFu + ((u >> 16) & 1u);
    return (unsigned short)(r >> 16);
}

static __device__ __forceinline__ short8 load_cvt(const float* __restrict__ p) {
    float4 x = *(const float4*)p;
    float4 y = *(const float4*)(p + 4);
    short8 a;
    a[0] = (short)f2bf(x.x); a[1] = (short)f2bf(x.y);
    a[2] = (short)f2bf(x.z); a[3] = (short)f2bf(x.w);
    a[4] = (short)f2bf(y.x); a[5] = (short)f2bf(y.y);
    a[6] = (short)f2bf(y.z); a[7] = (short)f2bf(y.w);
    return a;
}

// ---------------- New path: NC precompute + K=64 edge GEMM ----------------

// wpe: 8 frags of W[0:64,:]   (fi = kstep*4 + ct, ct in 0..3)
// wpn: 16 frags mapping nodes@[W[64:128] | W[128:192]] -> 128 cols (fi = kstep*8 + ct, ct in 0..7)
// gc : b + globals @ W[192:224]
__global__ void pack2_kernel(const float* __restrict__ W, const float* __restrict__ b,
                             const float* __restrict__ g,
                             unsigned short* __restrict__ wpe,
                             unsigned short* __restrict__ wpn,
                             float* __restrict__ gc) {
    int tid = blockIdx.x * 256 + threadIdx.x;
    if (tid < 512) {                       // 8 frags * 64 lanes
        int lane = tid & 63;
        int ct = (tid >> 6) & 3;
        int kstep = tid >> 8;
        int kbase = kstep * 32 + (lane >> 4) * 8;
        int col = ct * 16 + (lane & 15);
        short8 sv;
#pragma unroll
        for (int j = 0; j < 8; ++j)
            sv[j] = (short)f2bf(W[(size_t)(kbase + j) * D_OUT + col]);
        *(short8*)(wpe + (size_t)tid * 8) = sv;
    } else if (tid < 512 + 1024) {         // 16 frags * 64 lanes
        int t = tid - 512;
        int lane = t & 63;
        int ct = (t >> 6) & 7;
        int kstep = t >> 9;
        int kk = kstep * 32 + (lane >> 4) * 8;
        int c = ct * 16 + (lane & 15);
        int wrow = (c < 64) ? 64 : 128;    // recv block vs send block
        int wcol = c & 63;
        short8 sv;
#pragma unroll
        for (int j = 0; j < 8; ++j)
            sv[j] = (short)f2bf(W[(size_t)(wrow + kk + j) * D_OUT + wcol]);
        *(short8*)(wpn + (size_t)t * 8) = sv;
    } else if (tid < 512 + 1024 + 64) {
        int col = tid - 1536;
        float acc = b[col];
#pragma unroll
        for (int k = 0; k < 32; ++k)
            acc += g[k] * W[(size_t)(192 + k) * D_OUT + col];
        gc[col] = acc;
    }
}

// NC[i][0:64]  = nodes[i] @ W[64:128]
// NC[i][64:128]= nodes[i] @ W[128:192]
__global__ __launch_bounds__(256) void node_kernel(
    const float* __restrict__ nodes, const unsigned short* __restrict__ wpn,
    float* __restrict__ NC, int Nn) {
    const int lane = threadIdx.x & 63;
    const int wave = threadIdx.x >> 6;
    int nbase = blockIdx.x * 64 + wave * 16;
    if (nbase >= Nn) return;

    int na = nbase + (lane & 15);
    if (na >= Nn) na = Nn - 1;
    const float* pn = nodes + (size_t)na * D_NODE + (lane >> 4) * 8;
    short8 A0 = load_cvt(pn);
    short8 A1 = load_cvt(pn + 32);

    const int colbase = lane & 15;
    const int crow = nbase + (lane >> 4) * 4;

#pragma unroll
    for (int ct = 0; ct < 8; ++ct) {
        short8 B0 = *(const short8*)(wpn + ((size_t)(ct) * 64 + lane) * 8);
        short8 B1 = *(const short8*)(wpn + ((size_t)(8 + ct) * 64 + lane) * 8);
        floatx4 acc = (floatx4){0.f, 0.f, 0.f, 0.f};
        acc = __builtin_amdgcn_mfma_f32_16x16x32_bf16(A0, B0, acc, 0, 0, 0);
        acc = __builtin_amdgcn_mfma_f32_16x16x32_bf16(A1, B1, acc, 0, 0, 0);
#pragma unroll
        for (int r4 = 0; r4 < 4; ++r4) {
            int row = crow + r4;
            if (row < Nn)
                NC[(size_t)row * 128 + ct * 16 + colbase] = acc[r4];
        }
    }
}

__global__ __launch_bounds__(256) void edge2_kernel(
    const float* __restrict__ edges,
    const int* __restrict__ recv, const int* __restrict__ send,
    const unsigned short* __restrict__ wpe, const float* __restrict__ NC,
    const float* __restrict__ gc, float* __restrict__ out, int E) {

    const int lane = threadIdx.x & 63;
    const int wave = threadIdx.x >> 6;

    short8 Bf[8];
#pragma unroll
    for (int fi = 0; fi < 8; ++fi)
        Bf[fi] = *(const short8*)(wpe + ((size_t)fi * 64 + lane) * 8);

    const int colbase = lane & 15;
    float gv[4];
#pragma unroll
    for (int ct = 0; ct < 4; ++ct) gv[ct] = gc[ct * 16 + colbase];

    const int koff = (lane >> 4) * 8;

    for (int it = 0; it < ITERS; ++it) {
        int ebase = (blockIdx.x * ITERS + it) * 64 + wave * 16;
        if (ebase >= E) break;

        const int crow = ebase + (lane >> 4) * 4;

        // Issue index loads FIRST so gathers can start under the MFMA work.
        int ri[4], si[4];
#pragma unroll
        for (int r4 = 0; r4 < 4; ++r4) {
            int rr = crow + r4;
            if (rr >= E) rr = E - 1;
            ri[r4] = recv[rr];
            si[r4] = send[rr];
        }

        int ea = ebase + (lane & 15);
        if (ea >= E) ea = E - 1;
        const float* pe = edges + (size_t)ea * D_NODE + koff;
        short8 A0 = load_cvt(pe);
        short8 A1 = load_cvt(pe + 32);

        floatx4 acc[4];
#pragma unroll
        for (int ct = 0; ct < 4; ++ct)
            acc[ct] = (floatx4){gv[ct], gv[ct], gv[ct], gv[ct]};

#pragma unroll
        for (int ct = 0; ct < 4; ++ct) {
            acc[ct] = __builtin_amdgcn_mfma_f32_16x16x32_bf16(A0, Bf[ct], acc[ct], 0, 0, 0);
            acc[ct] = __builtin_amdgcn_mfma_f32_16x16x32_bf16(A1, Bf[4 + ct], acc[ct], 0, 0, 0);
        }

        // Gathered node contributions (f32, exact adds).
#pragma unroll
        for (int r4 = 0; r4 < 4; ++r4) {
            const float* prn = NC + (size_t)ri[r4] * 128 + colbase;
            const float* psn = NC + (size_t)si[r4] * 128 + 64 + colbase;
#pragma unroll
            for (int ct = 0; ct < 4; ++ct)
                acc[ct][r4] += prn[ct * 16] + psn[ct * 16];
        }

#pragma unroll
        for (int ct = 0; ct < 4; ++ct) {
#pragma unroll
            for (int r4 = 0; r4 < 4; ++r4) {
                int row = crow + r4;
                if (row < E)
                    out[(size_t)row * D_OUT + ct * 16 + colbase] = acc[ct][r4];
            }
        }
    }
}

// ---------------- Fallback path (round-1 kernel) if ws too small ----------------

#define NKSTEP 6
#define NFRAG  (NKSTEP * 4)

__global__ void pack_kernel(const float* __restrict__ W, const float* __restrict__ b,
                            const float* __restrict__ g,
                            unsigned short* __restrict__ wp, float* __restrict__ gc) {
    int tid = blockIdx.x * 256 + threadIdx.x;
    if (tid < NFRAG * 64) {
        int lane = tid & 63;
        int ct = (tid >> 6) & 3;
        int kstep = tid >> 8;
        int kbase = kstep * 32 + (lane >> 4) * 8;
        int col = ct * 16 + (lane & 15);
        short8 sv;
#pragma unroll
        for (int j = 0; j < 8; ++j)
            sv[j] = (short)f2bf(W[(size_t)(kbase + j) * D_OUT + col]);
        *(short8*)(wp + (size_t)tid * 8) = sv;
    } else if (tid < NFRAG * 64 + 64) {
        int col = tid - NFRAG * 64;
        float acc = b[col];
#pragma unroll
        for (int k = 0; k < 32; ++k)
            acc += g[k] * W[(size_t)(192 + k) * D_OUT + col];
        gc[col] = acc;
    }
}

__global__ __launch_bounds__(256) void edge_kernel(
    const float* __restrict__ edges, const float* __restrict__ nodes,
    const int* __restrict__ recv, const int* __restrict__ send,
    const unsigned short* __restrict__ wp, const float* __restrict__ gc,
    float* __restrict__ out, int E) {

    const int lane = threadIdx.x & 63;
    const int wave = threadIdx.x >> 6;

    short8 Bf[NFRAG];
#pragma unroll
    for (int fi = 0; fi < NFRAG; ++fi)
        Bf[fi] = *(const short8*)(wp + ((size_t)fi * 64 + lane) * 8);

    const int colbase = lane & 15;
    float gv[4];
#pragma unroll
    for (int ct = 0; ct < 4; ++ct) gv[ct] = gc[ct * 16 + colbase];

    const int koff = (lane >> 4) * 8;

    for (int it = 0; it < ITERS; ++it) {
        int ebase = (blockIdx.x * ITERS + it) * 64 + wave * 16;
        if (ebase >= E) break;

        int ea = ebase + (lane & 15);
        if (ea >= E) ea = E - 1;
        int ri = recv[ea];
        int si = send[ea];

        const float* pe = edges + (size_t)ea * D_NODE + koff;
        const float* pr = nodes + (size_t)ri * D_NODE + koff;
        const float* ps = nodes + (size_t)si * D_NODE + koff;

        short8 A[NKSTEP];
        A[0] = load_cvt(pe);
        A[1] = load_cvt(pe + 32);
        A[2] = load_cvt(pr);
        A[3] = load_cvt(pr + 32);
        A[4] = load_cvt(ps);
        A[5] = load_cvt(ps + 32);

        floatx4 acc[4];
#pragma unroll
        for (int ct = 0; ct < 4; ++ct)
            acc[ct] = (floatx4){gv[ct], gv[ct], gv[ct], gv[ct]};

#pragma unroll
        for (int ks = 0; ks < NKSTEP; ++ks) {
#pragma unroll
            for (int ct = 0; ct < 4; ++ct)
                acc[ct] = __builtin_amdgcn_mfma_f32_16x16x32_bf16(
                    A[ks], Bf[ks * 4 + ct], acc[ct], 0, 0, 0);
        }

        int crow = ebase + (lane >> 4) * 4;
#pragma unroll
        for (int ct = 0; ct < 4; ++ct) {
#pragma unroll
            for (int r4 = 0; r4 < 4; ++r4) {
                int row = crow + r4;
                if (row < E)
                    out[(size_t)row * D_OUT + ct * 16 + colbase] = acc[ct][r4];
            }
        }
    }
}

extern "C" void kernel_launch(void* const* d_in, const int* in_sizes, int n_in,
                              void* d_out, int out_size, void* d_ws, size_t ws_size,
                              hipStream_t stream) {
    const float* edges = (const float*)d_in[0];
    const float* nodes = (const float*)d_in[1];
    const float* glob  = (const float*)d_in[2];
    const int*   recv  = (const int*)d_in[3];
    const int*   send  = (const int*)d_in[4];
    const float* W     = (const float*)d_in[5];
    const float* b     = (const float*)d_in[6];
    float* out = (float*)d_out;

    int E  = in_sizes[0] / D_NODE;
    int Nn = in_sizes[1] / D_NODE;

    size_t nc_bytes  = (size_t)Nn * 128 * 4;
    size_t wpe_bytes = 512 * 8 * 2;    // 8192
    size_t wpn_bytes = 1024 * 8 * 2;   // 16384
    size_t need = nc_bytes + wpe_bytes + wpn_bytes + 256;

    int nblk = (E + ITERS * 64 - 1) / (ITERS * 64);

    if (ws_size >= need) {
        float* NC = (float*)d_ws;
        unsigned short* wpe = (unsigned short*)((char*)d_ws + nc_bytes);
        unsigned short* wpn = (unsigned short*)((char*)d_ws + nc_bytes + wpe_bytes);
        float* gc = (float*)((char*)d_ws + nc_bytes + wpe_bytes + wpn_bytes);

        pack2_kernel<<<7, 256, 0, stream>>>(W, b, glob, wpe, wpn, gc);
        node_kernel<<<(Nn + 63) / 64, 256, 0, stream>>>(nodes, wpn, NC, Nn);
        edge2_kernel<<<nblk, 256, 0, stream>>>(edges, recv, send, wpe, NC, gc, out, E);
    } else {
        unsigned short* wp = (unsigned short*)d_ws;
        float* gc = (float*)((char*)d_ws + NFRAG * 64 * 8 * 2);
        pack_kernel<<<7, 256, 0, stream>>>(W, b, glob, wp, gc);
        edge_kernel<<<nblk, 256, 0, stream>>>(edges, nodes, recv, send, wp, gc, out, E);
    }
}